// Round 2
// baseline (298.429 us; speedup 1.0000x reference)
//
#include <hip/hip_runtime.h>
#include <hip/hip_bf16.h>
#include <cmath>

typedef __bf16 bf16;
typedef __attribute__((ext_vector_type(8))) __bf16 bf16x8;
typedef __attribute__((ext_vector_type(4))) float f32x4;

#define B_ 2
#define S_ 2048
#define D_ 1024
#define N_ 16
#define H_ 64
#define LOG2E 1.44269504088896340736f

__device__ __forceinline__ void gload16(const bf16* g, bf16* l) {
  __builtin_amdgcn_global_load_lds(
      (const __attribute__((address_space(1))) void*)(g),
      (__attribute__((address_space(3))) void*)(l), 16, 0, 0);
}

__device__ __forceinline__ f32x4 mfma16(bf16x8 a, bf16x8 b, f32x4 c) {
  return __builtin_amdgcn_mfma_f32_16x16x32_bf16(a, b, c, 0, 0, 0);
}

__device__ __forceinline__ f32x4 zero4() {
  f32x4 v = {0.0f, 0.0f, 0.0f, 0.0f};
  return v;
}

// ---------------------------------------------------------------------------
// fp32 -> bf16 elementwise convert. n must be multiple of 8. grid-stride.
// ---------------------------------------------------------------------------
__global__ __launch_bounds__(256) void cvt_kernel(
    const float* __restrict__ in, bf16* __restrict__ out, int n8) {
  int id = blockIdx.x * 256 + threadIdx.x;
  if (id >= n8) return;
  const float4* p = (const float4*)(in + (size_t)id * 8);
  float4 v0 = p[0], v1 = p[1];
  bf16x8 o;
  o[0] = (bf16)v0.x; o[1] = (bf16)v0.y; o[2] = (bf16)v0.z; o[3] = (bf16)v0.w;
  o[4] = (bf16)v1.x; o[5] = (bf16)v1.y; o[6] = (bf16)v1.z; o[7] = (bf16)v1.w;
  *(bf16x8*)(out + (size_t)id * 8) = o;
}

// ---------------------------------------------------------------------------
// Transpose fp32 [R][C] -> bf16 [C][R], G matrices. grid (R/64, C/64, G), 256.
// ---------------------------------------------------------------------------
__global__ __launch_bounds__(256) void transpose_f32bf16_kernel(
    const float* __restrict__ in, bf16* __restrict__ out, int R, int C) {
  __shared__ bf16 t[64][72];
  const size_t mat = (size_t)R * C;
  const float* ing = in + (size_t)blockIdx.z * mat;
  bf16* outg = out + (size_t)blockIdx.z * mat;
  const int r0 = blockIdx.x * 64, c0 = blockIdx.y * 64;
  const int t8 = threadIdx.x & 7, trow = threadIdx.x >> 3;
#pragma unroll
  for (int p = 0; p < 2; ++p) {
    int r = trow + p * 32;
    const float4* src = (const float4*)(ing + (size_t)(r0 + r) * C + c0 + t8 * 8);
    float4 v0 = src[0], v1 = src[1];
    bf16x8 o;
    o[0] = (bf16)v0.x; o[1] = (bf16)v0.y; o[2] = (bf16)v0.z; o[3] = (bf16)v0.w;
    o[4] = (bf16)v1.x; o[5] = (bf16)v1.y; o[6] = (bf16)v1.z; o[7] = (bf16)v1.w;
    *(bf16x8*)(&t[r][t8 * 8]) = o;
  }
  __syncthreads();
#pragma unroll
  for (int p = 0; p < 2; ++p) {
    int c = trow + p * 32;
    bf16x8 v;
#pragma unroll
    for (int j = 0; j < 8; ++j) v[j] = t[t8 * 8 + j][c];
    *(bf16x8*)(outg + (size_t)(c0 + c) * R + r0 + t8 * 8) = v;
  }
}

// ---------------------------------------------------------------------------
// Transpose bf16 [R][C] -> bf16 [C][R], G matrices.
// ---------------------------------------------------------------------------
__global__ __launch_bounds__(256) void transpose_bf16_kernel(
    const bf16* __restrict__ in, bf16* __restrict__ out, int R, int C) {
  __shared__ bf16 t[64][72];
  const size_t mat = (size_t)R * C;
  const bf16* ing = in + (size_t)blockIdx.z * mat;
  bf16* outg = out + (size_t)blockIdx.z * mat;
  const int r0 = blockIdx.x * 64, c0 = blockIdx.y * 64;
  const int t8 = threadIdx.x & 7, trow = threadIdx.x >> 3;
#pragma unroll
  for (int p = 0; p < 2; ++p) {
    int r = trow + p * 32;
    bf16x8 v = *(const bf16x8*)(ing + (size_t)(r0 + r) * C + c0 + t8 * 8);
    *(bf16x8*)(&t[r][t8 * 8]) = v;
  }
  __syncthreads();
#pragma unroll
  for (int p = 0; p < 2; ++p) {
    int c = trow + p * 32;
    bf16x8 v;
#pragma unroll
    for (int j = 0; j < 8; ++j) v[j] = t[t8 * 8 + j][c];
    *(bf16x8*)(outg + (size_t)(c0 + c) * R + r0 + t8 * 8) = v;
  }
}

// ---------------------------------------------------------------------------
// QKV projection GEMM: A[4096x1024] bf16 x Bt[z] ([1024(c)][1024(k)] bf16).
// Epilogue scatters to proj[z][B][N][S][H] (bf16) + fp32 bias.
// grid (8, 32, 3), block 256 (4 waves, each 64x64 of the 128x128 tile).
// ---------------------------------------------------------------------------
__global__ __launch_bounds__(256) void gemm_proj_kernel(
    const bf16* __restrict__ A, const bf16* __restrict__ Wt_base,
    const float* __restrict__ bk, const float* __restrict__ bq,
    const float* __restrict__ bv, bf16* __restrict__ proj_base) {
  __shared__ bf16 As[128 * 64];
  __shared__ bf16 Bs[128 * 64];
  const int z = blockIdx.z;
  const bf16* Bt = Wt_base + (size_t)z * (1024 * 1024);
  const float* bias = (z == 0) ? bk : (z == 1 ? bq : bv);
  bf16* Out = proj_base + (size_t)z * ((size_t)B_ * N_ * S_ * H_);
  const int tid = threadIdx.x;
  const int w = tid >> 6, l = tid & 63, lan = l & 15, grp = l >> 4;
  const int mb = (w >> 1) * 64, nb = (w & 1) * 64;
  const int m0 = blockIdx.y * 128, n0 = blockIdx.x * 128;
  const int lrow8 = l >> 3, lcol8 = (l & 7) * 8;

  f32x4 acc[4][4];
#pragma unroll
  for (int i = 0; i < 4; ++i)
#pragma unroll
    for (int j = 0; j < 4; ++j) acc[i][j] = zero4();

  for (int kb = 0; kb < 1024; kb += 64) {
    __syncthreads();
#pragma unroll
    for (int i = 0; i < 4; ++i) {
      int ch = w * 4 + i;
      gload16(A + (size_t)(m0 + ch * 8 + lrow8) * 1024 + kb + lcol8, As + ch * 512);
      gload16(Bt + (size_t)(n0 + ch * 8 + lrow8) * 1024 + kb + lcol8, Bs + ch * 512);
    }
    __syncthreads();
#pragma unroll
    for (int kk = 0; kk < 2; ++kk) {
      bf16x8 a[4], b[4];
#pragma unroll
      for (int mf = 0; mf < 4; ++mf)
        a[mf] = *(const bf16x8*)(As + (mb + mf * 16 + lan) * 64 + grp * 8 + kk * 32);
#pragma unroll
      for (int nf = 0; nf < 4; ++nf)
        b[nf] = *(const bf16x8*)(Bs + (nb + nf * 16 + lan) * 64 + grp * 8 + kk * 32);
#pragma unroll
      for (int mf = 0; mf < 4; ++mf)
#pragma unroll
        for (int nf = 0; nf < 4; ++nf)
          acc[mf][nf] = mfma16(a[mf], b[nf], acc[mf][nf]);
    }
  }
#pragma unroll
  for (int nf = 0; nf < 4; ++nf) {
    int c = n0 + nb + nf * 16 + lan;
    float bs = bias[c];
    int n = c >> 6, h = c & 63;
#pragma unroll
    for (int mf = 0; mf < 4; ++mf) {
#pragma unroll
      for (int r = 0; r < 4; ++r) {
        int m = m0 + mb + mf * 16 + grp * 4 + r;
        int b = m >> 11, s = m & 2047;
        Out[((size_t)((b * N_ + n) * S_ + s)) * H_ + h] = (bf16)(acc[mf][nf][r] + bs);
      }
    }
  }
}

// ---------------------------------------------------------------------------
// Output projection GEMM: A = weighted [4096x1024] bf16, Bt = WoT bf16,
// Out = d_out [4096][1024] fp32, fp32 bias per column. grid (8, 32), 256.
// ---------------------------------------------------------------------------
__global__ __launch_bounds__(256) void gemm_out_kernel(
    const bf16* __restrict__ A, const bf16* __restrict__ Bt,
    const float* __restrict__ bias, float* __restrict__ Out) {
  __shared__ bf16 As[128 * 64];
  __shared__ bf16 Bs[128 * 64];
  const int tid = threadIdx.x;
  const int w = tid >> 6, l = tid & 63, lan = l & 15, grp = l >> 4;
  const int mb = (w >> 1) * 64, nb = (w & 1) * 64;
  const int m0 = blockIdx.y * 128, n0 = blockIdx.x * 128;
  const int lrow8 = l >> 3, lcol8 = (l & 7) * 8;

  f32x4 acc[4][4];
#pragma unroll
  for (int i = 0; i < 4; ++i)
#pragma unroll
    for (int j = 0; j < 4; ++j) acc[i][j] = zero4();

  for (int kb = 0; kb < 1024; kb += 64) {
    __syncthreads();
#pragma unroll
    for (int i = 0; i < 4; ++i) {
      int ch = w * 4 + i;
      gload16(A + (size_t)(m0 + ch * 8 + lrow8) * 1024 + kb + lcol8, As + ch * 512);
      gload16(Bt + (size_t)(n0 + ch * 8 + lrow8) * 1024 + kb + lcol8, Bs + ch * 512);
    }
    __syncthreads();
#pragma unroll
    for (int kk = 0; kk < 2; ++kk) {
      bf16x8 a[4], b[4];
#pragma unroll
      for (int mf = 0; mf < 4; ++mf)
        a[mf] = *(const bf16x8*)(As + (mb + mf * 16 + lan) * 64 + grp * 8 + kk * 32);
#pragma unroll
      for (int nf = 0; nf < 4; ++nf)
        b[nf] = *(const bf16x8*)(Bs + (nb + nf * 16 + lan) * 64 + grp * 8 + kk * 32);
#pragma unroll
      for (int mf = 0; mf < 4; ++mf)
#pragma unroll
        for (int nf = 0; nf < 4; ++nf)
          acc[mf][nf] = mfma16(a[mf], b[nf], acc[mf][nf]);
    }
  }
#pragma unroll
  for (int nf = 0; nf < 4; ++nf) {
    int c = n0 + nb + nf * 16 + lan;
    float bs = bias[c];
#pragma unroll
    for (int mf = 0; mf < 4; ++mf) {
#pragma unroll
      for (int r = 0; r < 4; ++r) {
        int m = m0 + mb + mf * 16 + grp * 4 + r;
        Out[(size_t)m * 1024 + c] = acc[mf][nf][r] + bs;
      }
    }
  }
}

// ---------------------------------------------------------------------------
// Attention (flash-style, FULL key range due to eps-mask quirk: masked scores
// participate in softmax with value ~0, so future keys DO get weight).
// Q/K: [B,N,S,H]; Vt: [B,N,H,S]; out weighted: [B*S][N*H] bf16.
// grid (S/128, N, B), block 256 (4 waves x 32 q-rows).
// ---------------------------------------------------------------------------
__global__ __launch_bounds__(256) void attn_kernel(
    const bf16* __restrict__ Qp, const bf16* __restrict__ Kp,
    const bf16* __restrict__ Vt, bf16* __restrict__ Wtd) {
  __shared__ bf16 Ks[64 * 64];
  __shared__ bf16 Vs[64 * 64];
  __shared__ bf16 Ps[4][32 * 72];
  const int tid = threadIdx.x;
  const int w = tid >> 6, l = tid & 63, lan = l & 15, grp = l >> 4;
  const int bn = blockIdx.z * N_ + blockIdx.y;
  const int qb = blockIdx.x * 128 + w * 32;
  const bf16* Qh = Qp + (size_t)bn * S_ * H_;
  const bf16* Kh = Kp + (size_t)bn * S_ * H_;
  const bf16* Vh = Vt + (size_t)bn * H_ * S_;
  const int lrow8 = l >> 3, lcol8 = (l & 7) * 8;

  // Q fragments in registers (A-operand layout: m=lan, k=grp*8+j (+32*kf))
  bf16x8 qa[2][2];
#pragma unroll
  for (int mf = 0; mf < 2; ++mf)
#pragma unroll
    for (int kf = 0; kf < 2; ++kf)
      qa[mf][kf] = *(const bf16x8*)(Qh + (size_t)(qb + mf * 16 + lan) * H_ + grp * 8 + kf * 32);

  f32x4 o[2][4];
  float mrow[2][4], lsum[2][4];
#pragma unroll
  for (int mf = 0; mf < 2; ++mf) {
#pragma unroll
    for (int hf = 0; hf < 4; ++hf) o[mf][hf] = zero4();
#pragma unroll
    for (int r = 0; r < 4; ++r) { mrow[mf][r] = -1e30f; lsum[mf][r] = 0.0f; }
  }

  for (int kt = 0; kt < 32; ++kt) {
    const int kb = kt * 64;
    __syncthreads();
#pragma unroll
    for (int i = 0; i < 2; ++i) {
      int ch = w * 2 + i;
      gload16(Kh + (size_t)(kb + ch * 8 + lrow8) * H_ + lcol8, Ks + ch * 512);
      gload16(Vh + (size_t)(ch * 8 + lrow8) * S_ + kb + lcol8, Vs + ch * 512);
    }
    __syncthreads();

    // --- QK^T: s[2][4] = 32q x 64k ---
    f32x4 s[2][4];
#pragma unroll
    for (int mf = 0; mf < 2; ++mf)
#pragma unroll
      for (int nf = 0; nf < 4; ++nf) s[mf][nf] = zero4();
#pragma unroll
    for (int kf = 0; kf < 2; ++kf) {
      bf16x8 kfr[4];
#pragma unroll
      for (int nf = 0; nf < 4; ++nf)
        kfr[nf] = *(const bf16x8*)(Ks + (nf * 16 + lan) * 64 + grp * 8 + kf * 32);
#pragma unroll
      for (int mf = 0; mf < 2; ++mf)
#pragma unroll
        for (int nf = 0; nf < 4; ++nf)
          s[mf][nf] = mfma16(qa[mf][kf], kfr[nf], s[mf][nf]);
    }

    // --- scale 1/8, eps-mask (0.0 for k>q), online softmax update ---
#pragma unroll
    for (int mf = 0; mf < 2; ++mf) {
#pragma unroll
      for (int r = 0; r < 4; ++r) {
        const int q_g = qb + mf * 16 + grp * 4 + r;
        float sv[4];
        float tmax = -1e30f;
#pragma unroll
        for (int nf = 0; nf < 4; ++nf) {
          int k_g = kb + nf * 16 + lan;
          float v = s[mf][nf][r] * 0.125f;
          if (k_g > q_g) v = 0.0f;  // EPS quirk: masked score ~0, kept in softmax
          sv[nf] = v;
          tmax = fmaxf(tmax, v);
        }
#pragma unroll
        for (int off = 1; off < 16; off <<= 1)
          tmax = fmaxf(tmax, __shfl_xor(tmax, off));
        float mo = mrow[mf][r];
        float mn = fmaxf(mo, tmax);
        float alpha = exp2f((mo - mn) * LOG2E);
        float rs = 0.0f;
#pragma unroll
        for (int nf = 0; nf < 4; ++nf) {
          float p = exp2f((sv[nf] - mn) * LOG2E);
          s[mf][nf][r] = p;
          rs += p;
        }
#pragma unroll
        for (int off = 1; off < 16; off <<= 1)
          rs += __shfl_xor(rs, off);
        lsum[mf][r] = lsum[mf][r] * alpha + rs;
        mrow[mf][r] = mn;
#pragma unroll
        for (int hf = 0; hf < 4; ++hf) o[mf][hf][r] *= alpha;
      }
    }

    // --- restage P as bf16 into per-wave LDS (C-layout -> A-layout) ---
    bf16* Pw = &Ps[w][0];
#pragma unroll
    for (int mf = 0; mf < 2; ++mf)
#pragma unroll
      for (int nf = 0; nf < 4; ++nf)
#pragma unroll
        for (int r = 0; r < 4; ++r)
          Pw[(mf * 16 + grp * 4 + r) * 72 + nf * 16 + lan] = (bf16)s[mf][nf][r];

    // --- PV: o += P(32x64) x V(64x64) ---
#pragma unroll
    for (int ks = 0; ks < 2; ++ks) {
      bf16x8 pa[2], vb[4];
#pragma unroll
      for (int mf = 0; mf < 2; ++mf)
        pa[mf] = *(const bf16x8*)(Pw + (mf * 16 + lan) * 72 + grp * 8 + ks * 32);
#pragma unroll
      for (int hf = 0; hf < 4; ++hf)
        vb[hf] = *(const bf16x8*)(Vs + (hf * 16 + lan) * 64 + grp * 8 + ks * 32);
#pragma unroll
      for (int mf = 0; mf < 2; ++mf)
#pragma unroll
        for (int hf = 0; hf < 4; ++hf)
          o[mf][hf] = mfma16(pa[mf], vb[hf], o[mf][hf]);
    }
  }

  // --- epilogue: normalize and write weighted [b*S+q][n*64+h] ---
  const size_t outbase = (size_t)blockIdx.z * S_ * (N_ * H_) + blockIdx.y * H_;
#pragma unroll
  for (int mf = 0; mf < 2; ++mf) {
#pragma unroll
    for (int r = 0; r < 4; ++r) {
      int q_g = qb + mf * 16 + grp * 4 + r;
      float inv = 1.0f / lsum[mf][r];
#pragma unroll
      for (int hf = 0; hf < 4; ++hf) {
        int h = hf * 16 + lan;
        Wtd[outbase + (size_t)q_g * (N_ * H_) + h] = (bf16)(o[mf][hf][r] * inv);
      }
    }
  }
}

// ---------------------------------------------------------------------------
extern "C" void kernel_launch(void* const* d_in, const int* in_sizes, int n_in,
                              void* d_out, int out_size, void* d_ws, size_t ws_size,
                              hipStream_t stream) {
  const float* residual = (const float*)d_in[0];
  const float* Wk = (const float*)d_in[1];
  const float* Wq = (const float*)d_in[2];
  const float* Wv = (const float*)d_in[3];
  const float* Wo = (const float*)d_in[4];
  const float* Bk = (const float*)d_in[5];
  const float* Bq = (const float*)d_in[6];
  const float* Bv = (const float*)d_in[7];
  const float* Bo = (const float*)d_in[8];
  float* outp = (float*)d_out;

  char* ws = (char*)d_ws;
  const size_t MB = 1024 * 1024;
  bf16* Abf = (bf16*)(ws + 0 * MB);        // [4096][1024] bf16 residual (8MB)
  bf16* Wkt = (bf16*)(ws + 8 * MB);        // 3 x [1024(c)][1024(d)] (6MB)
  bf16* Wot = (bf16*)(ws + 14 * MB);       // [1024(e)][1024(nh)] (2MB)
  bf16* Kp  = (bf16*)(ws + 16 * MB);       // [B][N][S][H] (8MB)
  bf16* Qp  = (bf16*)(ws + 24 * MB);       // (8MB)
  bf16* Vp  = (bf16*)(ws + 32 * MB);       // (8MB)
  bf16* Vtp = (bf16*)(ws + 40 * MB);       // [B][N][H][S] (8MB)
  bf16* Wtd = (bf16*)(ws + 0 * MB);        // [B*S][N*H] — aliases Abf (dead by then)
  (void)in_sizes; (void)n_in; (void)out_size; (void)ws_size;

  // residual fp32 -> bf16
  cvt_kernel<<<2048, 256, 0, stream>>>(residual, Abf, (B_ * S_ * D_) / 8);

  // weight transposes: per-head [D][H]->[H][D] (QKV, fp32->bf16), Wo [NH][D]->[D][NH]
  transpose_f32bf16_kernel<<<dim3(16, 1, 16), 256, 0, stream>>>(Wk, Wkt + 0 * MB, 1024, 64);
  transpose_f32bf16_kernel<<<dim3(16, 1, 16), 256, 0, stream>>>(Wq, Wkt + 1 * MB, 1024, 64);
  transpose_f32bf16_kernel<<<dim3(16, 1, 16), 256, 0, stream>>>(Wv, Wkt + 2 * MB, 1024, 64);
  transpose_f32bf16_kernel<<<dim3(16, 16, 1), 256, 0, stream>>>(Wo, Wot, 1024, 1024);

  // QKV projections (K->Kp, Q->Qp, V->Vp via z offsets)
  gemm_proj_kernel<<<dim3(8, 32, 3), 256, 0, stream>>>(Abf, Wkt, Bk, Bq, Bv, Kp);

  // V per-head transpose [S][H] -> [H][S]
  transpose_bf16_kernel<<<dim3(32, 1, 32), 256, 0, stream>>>(Vp, Vtp, 2048, 64);

  // attention (writes Wtd over the now-dead Abf region)
  attn_kernel<<<dim3(16, 16, 2), 256, 0, stream>>>(Qp, Kp, Vtp, Wtd);

  // output projection -> fp32 d_out
  gemm_out_kernel<<<dim3(8, 32, 1), 256, 0, stream>>>(Wtd, Wot, Bo, outp);

  (void)Qp; (void)Vp;
}

// Round 3
// 171.479 us; speedup vs baseline: 1.7403x; 1.7403x over previous
//
#include <hip/hip_runtime.h>
#include <hip/hip_bf16.h>
#include <cmath>

typedef __bf16 bf16;
typedef __attribute__((ext_vector_type(8))) __bf16 bf16x8;
typedef __attribute__((ext_vector_type(4))) float f32x4;

#define B_ 2
#define S_ 2048
#define D_ 1024
#define N_ 16
#define H_ 64
#define LOG2E 1.44269504088896340736f

__device__ __forceinline__ void gload16(const bf16* g, bf16* l) {
  __builtin_amdgcn_global_load_lds(
      (const __attribute__((address_space(1))) void*)(g),
      (__attribute__((address_space(3))) void*)(l), 16, 0, 0);
}

__device__ __forceinline__ f32x4 mfma16(bf16x8 a, bf16x8 b, f32x4 c) {
  return __builtin_amdgcn_mfma_f32_16x16x32_bf16(a, b, c, 0, 0, 0);
}

__device__ __forceinline__ f32x4 zero4() {
  f32x4 v = {0.0f, 0.0f, 0.0f, 0.0f};
  return v;
}

// ---------------------------------------------------------------------------
// fp32 -> bf16 elementwise convert. 8 elems/thread.
// ---------------------------------------------------------------------------
__global__ __launch_bounds__(256) void cvt_kernel(
    const float* __restrict__ in, bf16* __restrict__ out, int n8) {
  int id = blockIdx.x * 256 + threadIdx.x;
  if (id >= n8) return;
  const float4* p = (const float4*)(in + (size_t)id * 8);
  float4 v0 = p[0], v1 = p[1];
  bf16x8 o;
  o[0] = (bf16)v0.x; o[1] = (bf16)v0.y; o[2] = (bf16)v0.z; o[3] = (bf16)v0.w;
  o[4] = (bf16)v1.x; o[5] = (bf16)v1.y; o[6] = (bf16)v1.z; o[7] = (bf16)v1.w;
  *(bf16x8*)(out + (size_t)id * 8) = o;
}

// ---------------------------------------------------------------------------
// Transpose fp32 [R][C] -> bf16 [C][R], G matrices. grid (R/64, C/64, G), 256.
// ---------------------------------------------------------------------------
__global__ __launch_bounds__(256) void transpose_f32bf16_kernel(
    const float* __restrict__ in, bf16* __restrict__ out, int R, int C) {
  __shared__ bf16 t[64][72];
  const size_t mat = (size_t)R * C;
  const float* ing = in + (size_t)blockIdx.z * mat;
  bf16* outg = out + (size_t)blockIdx.z * mat;
  const int r0 = blockIdx.x * 64, c0 = blockIdx.y * 64;
  const int t8 = threadIdx.x & 7, trow = threadIdx.x >> 3;
#pragma unroll
  for (int p = 0; p < 2; ++p) {
    int r = trow + p * 32;
    const float4* src = (const float4*)(ing + (size_t)(r0 + r) * C + c0 + t8 * 8);
    float4 v0 = src[0], v1 = src[1];
    bf16x8 o;
    o[0] = (bf16)v0.x; o[1] = (bf16)v0.y; o[2] = (bf16)v0.z; o[3] = (bf16)v0.w;
    o[4] = (bf16)v1.x; o[5] = (bf16)v1.y; o[6] = (bf16)v1.z; o[7] = (bf16)v1.w;
    *(bf16x8*)(&t[r][t8 * 8]) = o;
  }
  __syncthreads();
#pragma unroll
  for (int p = 0; p < 2; ++p) {
    int c = trow + p * 32;
    bf16x8 v;
#pragma unroll
    for (int j = 0; j < 8; ++j) v[j] = t[t8 * 8 + j][c];
    *(bf16x8*)(outg + (size_t)(c0 + c) * R + r0 + t8 * 8) = v;
  }
}

// ---------------------------------------------------------------------------
// Transpose bf16 [R][C] -> bf16 [C][R], G matrices.
// ---------------------------------------------------------------------------
__global__ __launch_bounds__(256) void transpose_bf16_kernel(
    const bf16* __restrict__ in, bf16* __restrict__ out, int R, int C) {
  __shared__ bf16 t[64][72];
  const size_t mat = (size_t)R * C;
  const bf16* ing = in + (size_t)blockIdx.z * mat;
  bf16* outg = out + (size_t)blockIdx.z * mat;
  const int r0 = blockIdx.x * 64, c0 = blockIdx.y * 64;
  const int t8 = threadIdx.x & 7, trow = threadIdx.x >> 3;
#pragma unroll
  for (int p = 0; p < 2; ++p) {
    int r = trow + p * 32;
    bf16x8 v = *(const bf16x8*)(ing + (size_t)(r0 + r) * C + c0 + t8 * 8);
    *(bf16x8*)(&t[r][t8 * 8]) = v;
  }
  __syncthreads();
#pragma unroll
  for (int p = 0; p < 2; ++p) {
    int c = trow + p * 32;
    bf16x8 v;
#pragma unroll
    for (int j = 0; j < 8; ++j) v[j] = t[t8 * 8 + j][c];
    *(bf16x8*)(outg + (size_t)(c0 + c) * R + r0 + t8 * 8) = v;
  }
}

// ---------------------------------------------------------------------------
// Suffix-V: Suf[hd][q][h] = sum_{k>q} V[hd][k][h], fp32 (stored in d_out).
// K1: per-(hd, seg of 128) column totals. K2: scan within segment.
// ---------------------------------------------------------------------------
__global__ __launch_bounds__(64) void sufv_tot_kernel(
    const bf16* __restrict__ Vp, float* __restrict__ tot) {
  const int hd = blockIdx.x, seg = blockIdx.y, h = threadIdx.x;
  const bf16* Vh = Vp + (size_t)hd * S_ * H_;
  float a = 0.0f;
  for (int k = seg * 128; k < seg * 128 + 128; ++k) a += (float)Vh[(size_t)k * H_ + h];
  tot[(hd * 16 + seg) * 64 + h] = a;
}

__global__ __launch_bounds__(64) void sufv_scan_kernel(
    const bf16* __restrict__ Vp, const float* __restrict__ tot,
    float* __restrict__ Suf) {
  const int hd = blockIdx.x, seg = blockIdx.y, h = threadIdx.x;
  const bf16* Vh = Vp + (size_t)hd * S_ * H_;
  float* Sh = Suf + (size_t)hd * S_ * H_;
  float a = 0.0f;
  for (int s2 = seg + 1; s2 < 16; ++s2) a += tot[(hd * 16 + s2) * 64 + h];
  for (int k = seg * 128 + 127; k >= seg * 128; --k) {
    Sh[(size_t)k * H_ + h] = a;
    a += (float)Vh[(size_t)k * H_ + h];
  }
}

// ---------------------------------------------------------------------------
// QKV projection GEMM (swizzled LDS): A[4096x1024] bf16 x Bt[z].
// Epilogue scatters to proj[z][B][N][S][H] + fp32 bias. grid (8,32,3), 256.
// ---------------------------------------------------------------------------
__global__ __launch_bounds__(256) void gemm_proj_kernel(
    const bf16* __restrict__ A, const bf16* __restrict__ Wt_base,
    const float* __restrict__ bk, const float* __restrict__ bq,
    const float* __restrict__ bv, bf16* __restrict__ proj_base) {
  __shared__ bf16 As[128 * 64];
  __shared__ bf16 Bs[128 * 64];
  const int z = blockIdx.z;
  const bf16* Bt = Wt_base + (size_t)z * (1024 * 1024);
  const float* bias = (z == 0) ? bk : (z == 1 ? bq : bv);
  bf16* Out = proj_base + (size_t)z * ((size_t)B_ * N_ * S_ * H_);
  const int tid = threadIdx.x;
  const int w = tid >> 6, l = tid & 63, lan = l & 15, grp = l >> 4;
  const int mb = (w >> 1) * 64, nb = (w & 1) * 64;
  const int m0 = blockIdx.y * 128, n0 = blockIdx.x * 128;
  const int lrow8 = l >> 3;
  const int swl = ((l & 7) ^ lrow8) * 8;  // pre-swizzled source chunk
  const int l7 = lan & 7;

  f32x4 acc[4][4];
#pragma unroll
  for (int i = 0; i < 4; ++i)
#pragma unroll
    for (int j = 0; j < 4; ++j) acc[i][j] = zero4();

  for (int kb = 0; kb < 1024; kb += 64) {
    __syncthreads();
#pragma unroll
    for (int i = 0; i < 4; ++i) {
      int ch = w * 4 + i;
      gload16(A + (size_t)(m0 + ch * 8 + lrow8) * 1024 + kb + swl, As + ch * 512);
      gload16(Bt + (size_t)(n0 + ch * 8 + lrow8) * 1024 + kb + swl, Bs + ch * 512);
    }
    __syncthreads();
#pragma unroll
    for (int kk = 0; kk < 2; ++kk) {
      bf16x8 a[4], b[4];
#pragma unroll
      for (int mf = 0; mf < 4; ++mf)
        a[mf] = *(const bf16x8*)(As + (mb + mf * 16 + lan) * 64 + (((grp + kk * 4) ^ l7) << 3));
#pragma unroll
      for (int nf = 0; nf < 4; ++nf)
        b[nf] = *(const bf16x8*)(Bs + (nb + nf * 16 + lan) * 64 + (((grp + kk * 4) ^ l7) << 3));
#pragma unroll
      for (int mf = 0; mf < 4; ++mf)
#pragma unroll
        for (int nf = 0; nf < 4; ++nf)
          acc[mf][nf] = mfma16(a[mf], b[nf], acc[mf][nf]);
    }
  }
#pragma unroll
  for (int nf = 0; nf < 4; ++nf) {
    int c = n0 + nb + nf * 16 + lan;
    float bs = bias[c];
    int n = c >> 6, h = c & 63;
#pragma unroll
    for (int mf = 0; mf < 4; ++mf) {
#pragma unroll
      for (int r = 0; r < 4; ++r) {
        int m = m0 + mb + mf * 16 + grp * 4 + r;
        int b = m >> 11, s = m & 2047;
        Out[((size_t)((b * N_ + n) * S_ + s)) * H_ + h] = (bf16)(acc[mf][nf][r] + bs);
      }
    }
  }
}

// ---------------------------------------------------------------------------
// Output projection GEMM (swizzled LDS): weighted[4096x1024] x WoT -> fp32 out.
// ---------------------------------------------------------------------------
__global__ __launch_bounds__(256) void gemm_out_kernel(
    const bf16* __restrict__ A, const bf16* __restrict__ Bt,
    const float* __restrict__ bias, float* __restrict__ Out) {
  __shared__ bf16 As[128 * 64];
  __shared__ bf16 Bs[128 * 64];
  const int tid = threadIdx.x;
  const int w = tid >> 6, l = tid & 63, lan = l & 15, grp = l >> 4;
  const int mb = (w >> 1) * 64, nb = (w & 1) * 64;
  const int m0 = blockIdx.y * 128, n0 = blockIdx.x * 128;
  const int lrow8 = l >> 3;
  const int swl = ((l & 7) ^ lrow8) * 8;
  const int l7 = lan & 7;

  f32x4 acc[4][4];
#pragma unroll
  for (int i = 0; i < 4; ++i)
#pragma unroll
    for (int j = 0; j < 4; ++j) acc[i][j] = zero4();

  for (int kb = 0; kb < 1024; kb += 64) {
    __syncthreads();
#pragma unroll
    for (int i = 0; i < 4; ++i) {
      int ch = w * 4 + i;
      gload16(A + (size_t)(m0 + ch * 8 + lrow8) * 1024 + kb + swl, As + ch * 512);
      gload16(Bt + (size_t)(n0 + ch * 8 + lrow8) * 1024 + kb + swl, Bs + ch * 512);
    }
    __syncthreads();
#pragma unroll
    for (int kk = 0; kk < 2; ++kk) {
      bf16x8 a[4], b[4];
#pragma unroll
      for (int mf = 0; mf < 4; ++mf)
        a[mf] = *(const bf16x8*)(As + (mb + mf * 16 + lan) * 64 + (((grp + kk * 4) ^ l7) << 3));
#pragma unroll
      for (int nf = 0; nf < 4; ++nf)
        b[nf] = *(const bf16x8*)(Bs + (nb + nf * 16 + lan) * 64 + (((grp + kk * 4) ^ l7) << 3));
#pragma unroll
      for (int mf = 0; mf < 4; ++mf)
#pragma unroll
        for (int nf = 0; nf < 4; ++nf)
          acc[mf][nf] = mfma16(a[mf], b[nf], acc[mf][nf]);
    }
  }
#pragma unroll
  for (int nf = 0; nf < 4; ++nf) {
    int c = n0 + nb + nf * 16 + lan;
    float bs = bias[c];
#pragma unroll
    for (int mf = 0; mf < 4; ++mf) {
#pragma unroll
      for (int r = 0; r < 4; ++r) {
        int m = m0 + mb + mf * 16 + grp * 4 + r;
        Out[(size_t)m * 1024 + c] = acc[mf][nf][r] + bs;
      }
    }
  }
}

// ---------------------------------------------------------------------------
// Attention, causal-tiles only + analytic masked mass via suffix-V.
// No max-tracking (scores bounded; masked-> p=0, counted as (2047-q) in Z).
// Q/K: [hd][S][H]; Vt: [hd][H][S]; Suf fp32 [hd][S][H]; out Wtd [B*S][N*H].
// grid 512 (snake-balanced over (x=qtile, hd)), block 256 (4 waves x 32 rows).
// ---------------------------------------------------------------------------
__global__ __launch_bounds__(256) void attn_kernel(
    const bf16* __restrict__ Qp, const bf16* __restrict__ Kp,
    const bf16* __restrict__ Vt, const float* __restrict__ Suf,
    bf16* __restrict__ Wtd) {
  __shared__ bf16 Ks[64 * 64];
  __shared__ bf16 Vs[64 * 64];
  __shared__ bf16 Ps[4][32 * 72];
  const int tid = threadIdx.x;
  const int w = tid >> 6, l = tid & 63, lan = l & 15, grp = l >> 4;
  // snake-balanced (x, head) mapping: CU pair work sums to 34 tiles
  const int bi = blockIdx.x;
  int x, hd;
  if (bi < 256) { x = 15 - (bi >> 5); hd = bi & 31; }
  else { int j = bi - 256; x = j >> 5; hd = j & 31; }
  const int ktiles = 2 * x + 2;
  const int qb = x * 128;
  const int qw = qb + w * 32;
  const bf16* Qh = Qp + (size_t)hd * S_ * H_;
  const bf16* Kh = Kp + (size_t)hd * S_ * H_;
  const bf16* Vh = Vt + (size_t)hd * H_ * S_;
  const float* Sufh = Suf + (size_t)hd * S_ * H_;
  const int lrow8 = l >> 3;
  const int swl = ((l & 7) ^ lrow8) * 8;
  const int l7 = lan & 7;
  const float cexp = 0.125f * LOG2E;

  // Q fragments (A-operand: m=lan, k=grp*8+j (+32*kf))
  bf16x8 qa[2][2];
#pragma unroll
  for (int mf = 0; mf < 2; ++mf)
#pragma unroll
    for (int kf = 0; kf < 2; ++kf)
      qa[mf][kf] = *(const bf16x8*)(Qh + (size_t)(qw + mf * 16 + lan) * H_ + grp * 8 + kf * 32);

  f32x4 o[2][4];
  f32x4 psum[2];
#pragma unroll
  for (int mf = 0; mf < 2; ++mf) {
    psum[mf] = zero4();
#pragma unroll
    for (int hf = 0; hf < 4; ++hf) o[mf][hf] = zero4();
  }

  for (int kt = 0; kt < ktiles; ++kt) {
    const int kb = kt * 64;
    __syncthreads();
#pragma unroll
    for (int i2 = 0; i2 < 2; ++i2) {
      int ch = w * 2 + i2;
      gload16(Kh + (size_t)(kb + ch * 8 + lrow8) * H_ + swl, Ks + ch * 512);
      gload16(Vh + (size_t)(ch * 8 + lrow8) * S_ + kb + swl, Vs + ch * 512);
    }
    __syncthreads();
    if (kb > qw + 31) continue;  // this wave's rows all precede the tile

    // --- QK^T ---
    f32x4 s[2][4];
#pragma unroll
    for (int mf = 0; mf < 2; ++mf)
#pragma unroll
      for (int nf = 0; nf < 4; ++nf) s[mf][nf] = zero4();
    __builtin_amdgcn_s_setprio(1);
#pragma unroll
    for (int kf = 0; kf < 2; ++kf) {
      bf16x8 kfr[4];
#pragma unroll
      for (int nf = 0; nf < 4; ++nf)
        kfr[nf] = *(const bf16x8*)(Ks + (nf * 16 + lan) * 64 + (((grp + kf * 4) ^ l7) << 3));
#pragma unroll
      for (int mf = 0; mf < 2; ++mf)
#pragma unroll
        for (int nf = 0; nf < 4; ++nf)
          s[mf][nf] = mfma16(qa[mf][kf], kfr[nf], s[mf][nf]);
    }
    __builtin_amdgcn_s_setprio(0);

    // --- p = exp(s/8); diagonal tile: zero k>q (their mass is in Suf/Z) ---
    const bool maskt = (kb + 63 > qw);
#pragma unroll
    for (int mf = 0; mf < 2; ++mf) {
#pragma unroll
      for (int nf = 0; nf < 4; ++nf) {
        f32x4 p;
#pragma unroll
        for (int r = 0; r < 4; ++r) p[r] = exp2f(s[mf][nf][r] * cexp);
        if (maskt) {
          int k_g = kb + nf * 16 + lan;
#pragma unroll
          for (int r = 0; r < 4; ++r) {
            int q_g = qw + mf * 16 + grp * 4 + r;
            if (k_g > q_g) p[r] = 0.0f;
          }
        }
        psum[mf] += p;
        s[mf][nf] = p;
      }
    }

    // --- restage P (C-layout -> A-layout) in padded per-wave LDS ---
    bf16* Pw = &Ps[w][0];
#pragma unroll
    for (int mf = 0; mf < 2; ++mf)
#pragma unroll
      for (int nf = 0; nf < 4; ++nf)
#pragma unroll
        for (int r = 0; r < 4; ++r)
          Pw[(mf * 16 + grp * 4 + r) * 72 + nf * 16 + lan] = (bf16)s[mf][nf][r];

    // --- PV ---
    __builtin_amdgcn_s_setprio(1);
#pragma unroll
    for (int ks = 0; ks < 2; ++ks) {
      bf16x8 pa[2], vb[4];
#pragma unroll
      for (int mf = 0; mf < 2; ++mf)
        pa[mf] = *(const bf16x8*)(Pw + (mf * 16 + lan) * 72 + grp * 8 + ks * 32);
#pragma unroll
      for (int hf = 0; hf < 4; ++hf)
        vb[hf] = *(const bf16x8*)(Vs + (hf * 16 + lan) * 64 + (((grp + ks * 4) ^ l7) << 3));
#pragma unroll
      for (int mf = 0; mf < 2; ++mf)
#pragma unroll
        for (int hf = 0; hf < 4; ++hf)
          o[mf][hf] = mfma16(pa[mf], vb[hf], o[mf][hf]);
    }
    __builtin_amdgcn_s_setprio(0);
  }

  // --- single deferred row-sum reduce (16 lanes) ---
#pragma unroll
  for (int mf = 0; mf < 2; ++mf)
#pragma unroll
    for (int off = 1; off < 16; off <<= 1)
#pragma unroll
      for (int r = 0; r < 4; ++r)
        psum[mf][r] += __shfl_xor(psum[mf][r], off);

  // --- epilogue: o = (o_causal + SufV) / (psum + (2047-q)) ---
  const size_t outbase = (size_t)(hd >> 4) * S_ * (N_ * H_) + (size_t)(hd & 15) * H_;
#pragma unroll
  for (int mf = 0; mf < 2; ++mf) {
#pragma unroll
    for (int r = 0; r < 4; ++r) {
      int q_g = qw + mf * 16 + grp * 4 + r;
      float inv = 1.0f / (psum[mf][r] + (float)(2047 - q_g));
#pragma unroll
      for (int hf = 0; hf < 4; ++hf) {
        int h = hf * 16 + lan;
        float suf = Sufh[(size_t)q_g * H_ + h];
        Wtd[outbase + (size_t)q_g * (N_ * H_) + h] = (bf16)((o[mf][hf][r] + suf) * inv);
      }
    }
  }
}

// ---------------------------------------------------------------------------
extern "C" void kernel_launch(void* const* d_in, const int* in_sizes, int n_in,
                              void* d_out, int out_size, void* d_ws, size_t ws_size,
                              hipStream_t stream) {
  const float* residual = (const float*)d_in[0];
  const float* Wk = (const float*)d_in[1];
  const float* Wq = (const float*)d_in[2];
  const float* Wv = (const float*)d_in[3];
  const float* Wo = (const float*)d_in[4];
  const float* Bk = (const float*)d_in[5];
  const float* Bq = (const float*)d_in[6];
  const float* Bv = (const float*)d_in[7];
  const float* Bo = (const float*)d_in[8];
  float* outp = (float*)d_out;

  char* ws = (char*)d_ws;
  const size_t MB = 1024 * 1024;
  bf16* Abf = (bf16*)(ws + 0 * MB);    // [4096][1024] bf16 (8MB); later Wtd
  bf16* Wot = (bf16*)(ws + 8 * MB);    // [1024(e)][1024(nh)] (2MB, live to end)
  bf16* Wkt = (bf16*)(ws + 10 * MB);   // 3 x [1024][1024] (6MB)
  bf16* Kp  = (bf16*)(ws + 16 * MB);   // [hd][S][H] (8MB)
  bf16* Qp  = (bf16*)(ws + 24 * MB);   // (8MB)
  bf16* Vp  = (bf16*)(ws + 32 * MB);   // (8MB)
  bf16* Vtp = (bf16*)(ws + 40 * MB);   // [hd][H][S] (8MB)
  float* tot = (float*)(ws + 48 * MB); // [32][16][64] fp32 (128KB)
  bf16* Wtd = Abf;                     // aliases Abf (dead after gemm_proj)
  float* Suf = (float*)d_out;          // d_out as fp32 scratch until gemm_out
  (void)in_sizes; (void)n_in; (void)out_size; (void)ws_size;

  // residual fp32 -> bf16
  cvt_kernel<<<2048, 256, 0, stream>>>(residual, Abf, (B_ * S_ * D_) / 8);

  // weight transposes
  transpose_f32bf16_kernel<<<dim3(16, 1, 16), 256, 0, stream>>>(Wk, Wkt + 0 * MB, 1024, 64);
  transpose_f32bf16_kernel<<<dim3(16, 1, 16), 256, 0, stream>>>(Wq, Wkt + 1 * MB, 1024, 64);
  transpose_f32bf16_kernel<<<dim3(16, 1, 16), 256, 0, stream>>>(Wv, Wkt + 2 * MB, 1024, 64);
  transpose_f32bf16_kernel<<<dim3(16, 16, 1), 256, 0, stream>>>(Wo, Wot, 1024, 1024);

  // QKV projections (K->Kp, Q->Qp, V->Vp)
  gemm_proj_kernel<<<dim3(8, 32, 3), 256, 0, stream>>>(Abf, Wkt, Bk, Bq, Bv, Kp);

  // suffix-V (masked-mass numerator), fp32 into d_out scratch
  sufv_tot_kernel<<<dim3(32, 16), 64, 0, stream>>>(Vp, tot);
  sufv_scan_kernel<<<dim3(32, 16), 64, 0, stream>>>(Vp, tot, Suf);

  // V per-head transpose [S][H] -> [H][S]
  transpose_bf16_kernel<<<dim3(32, 1, 32), 256, 0, stream>>>(Vp, Vtp, 2048, 64);

  // attention (causal tiles only; writes Wtd over dead Abf)
  attn_kernel<<<512, 256, 0, stream>>>(Qp, Kp, Vtp, Suf, Wtd);

  // output projection -> fp32 d_out (overwrites Suf scratch)
  gemm_out_kernel<<<dim3(8, 32, 1), 256, 0, stream>>>(Wtd, Wot, Bo, outp);

  (void)Qp;
}

// Round 4
// 164.375 us; speedup vs baseline: 1.8155x; 1.0432x over previous
//
#include <hip/hip_runtime.h>
#include <hip/hip_bf16.h>
#include <cmath>

typedef __bf16 bf16;
typedef __attribute__((ext_vector_type(8))) __bf16 bf16x8;
typedef __attribute__((ext_vector_type(4))) float f32x4;

#define B_ 2
#define S_ 2048
#define D_ 1024
#define N_ 16
#define H_ 64
#define LOG2E 1.44269504088896340736f

__device__ __forceinline__ void gload16(const bf16* g, bf16* l) {
  __builtin_amdgcn_global_load_lds(
      (const __attribute__((address_space(1))) void*)(g),
      (__attribute__((address_space(3))) void*)(l), 16, 0, 0);
}

__device__ __forceinline__ f32x4 mfma16(bf16x8 a, bf16x8 b, f32x4 c) {
  return __builtin_amdgcn_mfma_f32_16x16x32_bf16(a, b, c, 0, 0, 0);
}

__device__ __forceinline__ f32x4 zero4() {
  f32x4 v = {0.0f, 0.0f, 0.0f, 0.0f};
  return v;
}

// ---------------------------------------------------------------------------
// fp32 -> bf16 elementwise convert. 8 elems/thread.
// ---------------------------------------------------------------------------
__global__ __launch_bounds__(256) void cvt_kernel(
    const float* __restrict__ in, bf16* __restrict__ out, int n8) {
  int id = blockIdx.x * 256 + threadIdx.x;
  if (id >= n8) return;
  const float4* p = (const float4*)(in + (size_t)id * 8);
  float4 v0 = p[0], v1 = p[1];
  bf16x8 o;
  o[0] = (bf16)v0.x; o[1] = (bf16)v0.y; o[2] = (bf16)v0.z; o[3] = (bf16)v0.w;
  o[4] = (bf16)v1.x; o[5] = (bf16)v1.y; o[6] = (bf16)v1.z; o[7] = (bf16)v1.w;
  *(bf16x8*)(out + (size_t)id * 8) = o;
}

// ---------------------------------------------------------------------------
// Merged QKV weight transpose: head z (0..47) of {Wk,Wq,Wv}, [1024][64] fp32
// -> [64][1024] bf16 at out + z*64*1024. grid (16, 1, 48), block 256.
// ---------------------------------------------------------------------------
__global__ __launch_bounds__(256) void qkvw_transpose_kernel(
    const float* __restrict__ Wk, const float* __restrict__ Wq,
    const float* __restrict__ Wv, bf16* __restrict__ out) {
  __shared__ bf16 t[64][72];
  const int z = blockIdx.z;
  const float* W = (z < 16) ? Wk : (z < 32) ? Wq : Wv;
  const float* ing = W + (size_t)(z & 15) * (1024 * 64);
  bf16* outg = out + (size_t)z * (64 * 1024);
  const int r0 = blockIdx.x * 64;
  const int t8 = threadIdx.x & 7, trow = threadIdx.x >> 3;
#pragma unroll
  for (int p = 0; p < 2; ++p) {
    int r = trow + p * 32;
    const float4* src = (const float4*)(ing + (size_t)(r0 + r) * 64 + t8 * 8);
    float4 v0 = src[0], v1 = src[1];
    bf16x8 o;
    o[0] = (bf16)v0.x; o[1] = (bf16)v0.y; o[2] = (bf16)v0.z; o[3] = (bf16)v0.w;
    o[4] = (bf16)v1.x; o[5] = (bf16)v1.y; o[6] = (bf16)v1.z; o[7] = (bf16)v1.w;
    *(bf16x8*)(&t[r][t8 * 8]) = o;
  }
  __syncthreads();
#pragma unroll
  for (int p = 0; p < 2; ++p) {
    int c = trow + p * 32;
    bf16x8 v;
#pragma unroll
    for (int j = 0; j < 8; ++j) v[j] = t[t8 * 8 + j][c];
    *(bf16x8*)(outg + (size_t)c * 1024 + r0 + t8 * 8) = v;
  }
}

// ---------------------------------------------------------------------------
// Transpose fp32 [R][C] -> bf16 [C][R], G matrices. grid (R/64, C/64, G), 256.
// ---------------------------------------------------------------------------
__global__ __launch_bounds__(256) void transpose_f32bf16_kernel(
    const float* __restrict__ in, bf16* __restrict__ out, int R, int C) {
  __shared__ bf16 t[64][72];
  const size_t mat = (size_t)R * C;
  const float* ing = in + (size_t)blockIdx.z * mat;
  bf16* outg = out + (size_t)blockIdx.z * mat;
  const int r0 = blockIdx.x * 64, c0 = blockIdx.y * 64;
  const int t8 = threadIdx.x & 7, trow = threadIdx.x >> 3;
#pragma unroll
  for (int p = 0; p < 2; ++p) {
    int r = trow + p * 32;
    const float4* src = (const float4*)(ing + (size_t)(r0 + r) * C + c0 + t8 * 8);
    float4 v0 = src[0], v1 = src[1];
    bf16x8 o;
    o[0] = (bf16)v0.x; o[1] = (bf16)v0.y; o[2] = (bf16)v0.z; o[3] = (bf16)v0.w;
    o[4] = (bf16)v1.x; o[5] = (bf16)v1.y; o[6] = (bf16)v1.z; o[7] = (bf16)v1.w;
    *(bf16x8*)(&t[r][t8 * 8]) = o;
  }
  __syncthreads();
#pragma unroll
  for (int p = 0; p < 2; ++p) {
    int c = trow + p * 32;
    bf16x8 v;
#pragma unroll
    for (int j = 0; j < 8; ++j) v[j] = t[t8 * 8 + j][c];
    *(bf16x8*)(outg + (size_t)(c0 + c) * R + r0 + t8 * 8) = v;
  }
}

// ---------------------------------------------------------------------------
// Transpose bf16 [R][C] -> bf16 [C][R], G matrices.
// ---------------------------------------------------------------------------
__global__ __launch_bounds__(256) void transpose_bf16_kernel(
    const bf16* __restrict__ in, bf16* __restrict__ out, int R, int C) {
  __shared__ bf16 t[64][72];
  const size_t mat = (size_t)R * C;
  const bf16* ing = in + (size_t)blockIdx.z * mat;
  bf16* outg = out + (size_t)blockIdx.z * mat;
  const int r0 = blockIdx.x * 64, c0 = blockIdx.y * 64;
  const int t8 = threadIdx.x & 7, trow = threadIdx.x >> 3;
#pragma unroll
  for (int p = 0; p < 2; ++p) {
    int r = trow + p * 32;
    bf16x8 v = *(const bf16x8*)(ing + (size_t)(r0 + r) * C + c0 + t8 * 8);
    *(bf16x8*)(&t[r][t8 * 8]) = v;
  }
  __syncthreads();
#pragma unroll
  for (int p = 0; p < 2; ++p) {
    int c = trow + p * 32;
    bf16x8 v;
#pragma unroll
    for (int j = 0; j < 8; ++j) v[j] = t[t8 * 8 + j][c];
    *(bf16x8*)(outg + (size_t)(c0 + c) * R + r0 + t8 * 8) = v;
  }
}

// ---------------------------------------------------------------------------
// Suffix-V: Suf[hd][q][h] = sum_{k>q} V[hd][k][h], fp32 (stored in d_out).
// ---------------------------------------------------------------------------
__global__ __launch_bounds__(64) void sufv_tot_kernel(
    const bf16* __restrict__ Vp, float* __restrict__ tot) {
  const int hd = blockIdx.x, seg = blockIdx.y, h = threadIdx.x;
  const bf16* Vh = Vp + (size_t)hd * S_ * H_;
  float a = 0.0f;
  for (int k = seg * 128; k < seg * 128 + 128; ++k) a += (float)Vh[(size_t)k * H_ + h];
  tot[(hd * 16 + seg) * 64 + h] = a;
}

__global__ __launch_bounds__(64) void sufv_scan_kernel(
    const bf16* __restrict__ Vp, const float* __restrict__ tot,
    float* __restrict__ Suf) {
  const int hd = blockIdx.x, seg = blockIdx.y, h = threadIdx.x;
  const bf16* Vh = Vp + (size_t)hd * S_ * H_;
  float* Sh = Suf + (size_t)hd * S_ * H_;
  float a = 0.0f;
  for (int s2 = seg + 1; s2 < 16; ++s2) a += tot[(hd * 16 + s2) * 64 + h];
  for (int k = seg * 128 + 127; k >= seg * 128; --k) {
    Sh[(size_t)k * H_ + h] = a;
    a += (float)Vh[(size_t)k * H_ + h];
  }
}

// ---------------------------------------------------------------------------
// QKV projection GEMM (swizzled LDS): A[4096x1024] bf16 x Bt[z].
// Epilogue scatters to proj[z][B][N][S][H] + fp32 bias. grid (8,32,3), 256.
// ---------------------------------------------------------------------------
__global__ __launch_bounds__(256) void gemm_proj_kernel(
    const bf16* __restrict__ A, const bf16* __restrict__ Wt_base,
    const float* __restrict__ bk, const float* __restrict__ bq,
    const float* __restrict__ bv, bf16* __restrict__ proj_base) {
  __shared__ bf16 As[128 * 64];
  __shared__ bf16 Bs[128 * 64];
  const int z = blockIdx.z;
  const bf16* Bt = Wt_base + (size_t)z * (1024 * 1024);
  const float* bias = (z == 0) ? bk : (z == 1 ? bq : bv);
  bf16* Out = proj_base + (size_t)z * ((size_t)B_ * N_ * S_ * H_);
  const int tid = threadIdx.x;
  const int w = tid >> 6, l = tid & 63, lan = l & 15, grp = l >> 4;
  const int mb = (w >> 1) * 64, nb = (w & 1) * 64;
  const int m0 = blockIdx.y * 128, n0 = blockIdx.x * 128;
  const int lrow8 = l >> 3;
  const int swl = ((l & 7) ^ lrow8) * 8;
  const int l7 = lan & 7;

  f32x4 acc[4][4];
#pragma unroll
  for (int i = 0; i < 4; ++i)
#pragma unroll
    for (int j = 0; j < 4; ++j) acc[i][j] = zero4();

  for (int kb = 0; kb < 1024; kb += 64) {
    __syncthreads();
#pragma unroll
    for (int i = 0; i < 4; ++i) {
      int ch = w * 4 + i;
      gload16(A + (size_t)(m0 + ch * 8 + lrow8) * 1024 + kb + swl, As + ch * 512);
      gload16(Bt + (size_t)(n0 + ch * 8 + lrow8) * 1024 + kb + swl, Bs + ch * 512);
    }
    __syncthreads();
#pragma unroll
    for (int kk = 0; kk < 2; ++kk) {
      bf16x8 a[4], b[4];
#pragma unroll
      for (int mf = 0; mf < 4; ++mf)
        a[mf] = *(const bf16x8*)(As + (mb + mf * 16 + lan) * 64 + (((grp + kk * 4) ^ l7) << 3));
#pragma unroll
      for (int nf = 0; nf < 4; ++nf)
        b[nf] = *(const bf16x8*)(Bs + (nb + nf * 16 + lan) * 64 + (((grp + kk * 4) ^ l7) << 3));
#pragma unroll
      for (int mf = 0; mf < 4; ++mf)
#pragma unroll
        for (int nf = 0; nf < 4; ++nf)
          acc[mf][nf] = mfma16(a[mf], b[nf], acc[mf][nf]);
    }
  }
#pragma unroll
  for (int nf = 0; nf < 4; ++nf) {
    int c = n0 + nb + nf * 16 + lan;
    float bs = bias[c];
    int n = c >> 6, h = c & 63;
#pragma unroll
    for (int mf = 0; mf < 4; ++mf) {
#pragma unroll
      for (int r = 0; r < 4; ++r) {
        int m = m0 + mb + mf * 16 + grp * 4 + r;
        int b = m >> 11, s = m & 2047;
        Out[((size_t)((b * N_ + n) * S_ + s)) * H_ + h] = (bf16)(acc[mf][nf][r] + bs);
      }
    }
  }
}

// ---------------------------------------------------------------------------
// Output projection GEMM (swizzled LDS): weighted[4096x1024] x WoT -> fp32 out.
// ---------------------------------------------------------------------------
__global__ __launch_bounds__(256) void gemm_out_kernel(
    const bf16* __restrict__ A, const bf16* __restrict__ Bt,
    const float* __restrict__ bias, float* __restrict__ Out) {
  __shared__ bf16 As[128 * 64];
  __shared__ bf16 Bs[128 * 64];
  const int tid = threadIdx.x;
  const int w = tid >> 6, l = tid & 63, lan = l & 15, grp = l >> 4;
  const int mb = (w >> 1) * 64, nb = (w & 1) * 64;
  const int m0 = blockIdx.y * 128, n0 = blockIdx.x * 128;
  const int lrow8 = l >> 3;
  const int swl = ((l & 7) ^ lrow8) * 8;
  const int l7 = lan & 7;

  f32x4 acc[4][4];
#pragma unroll
  for (int i = 0; i < 4; ++i)
#pragma unroll
    for (int j = 0; j < 4; ++j) acc[i][j] = zero4();

  for (int kb = 0; kb < 1024; kb += 64) {
    __syncthreads();
#pragma unroll
    for (int i = 0; i < 4; ++i) {
      int ch = w * 4 + i;
      gload16(A + (size_t)(m0 + ch * 8 + lrow8) * 1024 + kb + swl, As + ch * 512);
      gload16(Bt + (size_t)(n0 + ch * 8 + lrow8) * 1024 + kb + swl, Bs + ch * 512);
    }
    __syncthreads();
#pragma unroll
    for (int kk = 0; kk < 2; ++kk) {
      bf16x8 a[4], b[4];
#pragma unroll
      for (int mf = 0; mf < 4; ++mf)
        a[mf] = *(const bf16x8*)(As + (mb + mf * 16 + lan) * 64 + (((grp + kk * 4) ^ l7) << 3));
#pragma unroll
      for (int nf = 0; nf < 4; ++nf)
        b[nf] = *(const bf16x8*)(Bs + (nb + nf * 16 + lan) * 64 + (((grp + kk * 4) ^ l7) << 3));
#pragma unroll
      for (int mf = 0; mf < 4; ++mf)
#pragma unroll
        for (int nf = 0; nf < 4; ++nf)
          acc[mf][nf] = mfma16(a[mf], b[nf], acc[mf][nf]);
    }
  }
#pragma unroll
  for (int nf = 0; nf < 4; ++nf) {
    int c = n0 + nb + nf * 16 + lan;
    float bs = bias[c];
#pragma unroll
    for (int mf = 0; mf < 4; ++mf) {
#pragma unroll
      for (int r = 0; r < 4; ++r) {
        int m = m0 + mb + mf * 16 + grp * 4 + r;
        Out[(size_t)m * 1024 + c] = acc[mf][nf][r] + bs;
      }
    }
  }
}

// ---------------------------------------------------------------------------
// Attention v3: swapped QK^T (lane-local P rows) + packed b64 P-restage +
// double-buffered K/V staging with raw barriers and counted vmcnt.
// Causal tiles only; masked mass added analytically via suffix-V.
// grid 512 (snake-balanced), block 256 (4 waves x 32 q-rows).
// ---------------------------------------------------------------------------
__global__ __launch_bounds__(256) void attn_kernel(
    const bf16* __restrict__ Qp, const bf16* __restrict__ Kp,
    const bf16* __restrict__ Vt, const float* __restrict__ Suf,
    bf16* __restrict__ Wtd) {
  __shared__ bf16 Ks[2][64 * 64];
  __shared__ bf16 Vs[2][64 * 64];
  __shared__ bf16 Ps[4][32 * 72];
  const int tid = threadIdx.x;
  const int w = tid >> 6, l = tid & 63, lan = l & 15, grp = l >> 4;
  const int bi = blockIdx.x;
  int x, hd;
  if (bi < 256) { x = 15 - (bi >> 5); hd = bi & 31; }
  else { int j = bi - 256; x = j >> 5; hd = j & 31; }
  const int ktiles = 2 * x + 2;
  const int qw = x * 128 + w * 32;
  const bf16* Qh = Qp + (size_t)hd * S_ * H_;
  const bf16* Kh = Kp + (size_t)hd * S_ * H_;
  const bf16* Vh = Vt + (size_t)hd * H_ * S_;
  const float* Sufh = Suf + (size_t)hd * S_ * H_;
  const int lrow8 = l >> 3;
  const int swl = ((l & 7) ^ lrow8) * 8;
  const int l7 = lan & 7;
  const float cexp = 0.125f * LOG2E;

#define STAGE(buf, kb_)                                                        \
  do {                                                                         \
    _Pragma("unroll") for (int i2 = 0; i2 < 2; ++i2) {                         \
      int ch = w * 2 + i2;                                                     \
      gload16(Kh + (size_t)((kb_) + ch * 8 + lrow8) * H_ + swl,                \
              &Ks[buf][ch * 512]);                                             \
      gload16(Vh + (size_t)(ch * 8 + lrow8) * S_ + (kb_) + swl,                \
              &Vs[buf][ch * 512]);                                             \
    }                                                                          \
  } while (0)

  // Q fragments (used as B-operand: n=lan=q, k=grp*8+j (+32*kf))
  bf16x8 qa[2][2];
#pragma unroll
  for (int qt = 0; qt < 2; ++qt)
#pragma unroll
    for (int kf = 0; kf < 2; ++kf)
      qa[qt][kf] = *(const bf16x8*)(Qh + (size_t)(qw + qt * 16 + lan) * H_ + grp * 8 + kf * 32);

  f32x4 o[2][4];
  float psum[2] = {0.0f, 0.0f};
#pragma unroll
  for (int qt = 0; qt < 2; ++qt)
#pragma unroll
    for (int hf = 0; hf < 4; ++hf) o[qt][hf] = zero4();

  bf16* Pw = &Ps[w][0];

  STAGE(0, 0);
  for (int tt = 0; tt < ktiles; ++tt) {
    const int kb = tt * 64;
    const int cur = tt & 1;
    if (tt + 1 < ktiles) {
      STAGE(cur ^ 1, kb + 64);
      asm volatile("s_waitcnt vmcnt(4)" ::: "memory");
    } else {
      asm volatile("s_waitcnt vmcnt(0)" ::: "memory");
    }
    __builtin_amdgcn_s_barrier();

    if (kb <= qw + 31) {
      const bf16* Kc = &Ks[cur][0];
      const bf16* Vc = &Vs[cur][0];

      // --- swapped QK^T: s2[k2][qt], col=lan=q, row=grp*4+r=k ---
      f32x4 s2[4][2];
#pragma unroll
      for (int k2 = 0; k2 < 4; ++k2)
#pragma unroll
        for (int qt = 0; qt < 2; ++qt) s2[k2][qt] = zero4();
      __builtin_amdgcn_s_setprio(1);
#pragma unroll
      for (int kf = 0; kf < 2; ++kf) {
        bf16x8 kfr[4];
#pragma unroll
        for (int k2 = 0; k2 < 4; ++k2)
          kfr[k2] = *(const bf16x8*)(Kc + (k2 * 16 + lan) * 64 + (((grp + kf * 4) ^ l7) << 3));
#pragma unroll
        for (int k2 = 0; k2 < 4; ++k2)
#pragma unroll
          for (int qt = 0; qt < 2; ++qt)
            s2[k2][qt] = mfma16(kfr[k2], qa[qt][kf], s2[k2][qt]);
      }
      __builtin_amdgcn_s_setprio(0);

      // --- exp, mask (diag tile), psum, pack two cvt_pk -> one b64 write ---
      const bool maskt = (kb + 63 > qw);
#pragma unroll
      for (int qt = 0; qt < 2; ++qt) {
        const int q_g = qw + qt * 16 + lan;
#pragma unroll
        for (int k2 = 0; k2 < 4; ++k2) {
          f32x4 p;
#pragma unroll
          for (int r = 0; r < 4; ++r) p[r] = exp2f(s2[k2][qt][r] * cexp);
          if (maskt) {
            const int kg0 = kb + k2 * 16 + grp * 4;
#pragma unroll
            for (int r = 0; r < 4; ++r)
              if (kg0 + r > q_g) p[r] = 0.0f;
          }
          psum[qt] += (p[0] + p[1]) + (p[2] + p[3]);
          unsigned plo, phi;
          asm("v_cvt_pk_bf16_f32 %0, %1, %2" : "=v"(plo) : "v"(p[0]), "v"(p[1]));
          asm("v_cvt_pk_bf16_f32 %0, %1, %2" : "=v"(phi) : "v"(p[2]), "v"(p[3]));
          uint2 u; u.x = plo; u.y = phi;
          *(uint2*)(Pw + (qt * 16 + lan) * 72 + k2 * 16 + grp * 4) = u;
        }
      }

      // --- PV: o[qt][hf] += P(32x64) x V(64x64) ---
      __builtin_amdgcn_s_setprio(1);
#pragma unroll
      for (int ks = 0; ks < 2; ++ks) {
        bf16x8 pa[2], vb[4];
#pragma unroll
        for (int qt = 0; qt < 2; ++qt)
          pa[qt] = *(const bf16x8*)(Pw + (qt * 16 + lan) * 72 + grp * 8 + ks * 32);
#pragma unroll
        for (int hf = 0; hf < 4; ++hf)
          vb[hf] = *(const bf16x8*)(Vc + (hf * 16 + lan) * 64 + (((grp + ks * 4) ^ l7) << 3));
#pragma unroll
        for (int qt = 0; qt < 2; ++qt)
#pragma unroll
          for (int hf = 0; hf < 4; ++hf)
            o[qt][hf] = mfma16(pa[qt], vb[hf], o[qt][hf]);
      }
      __builtin_amdgcn_s_setprio(0);
    }
    __builtin_amdgcn_s_barrier();
  }
#undef STAGE

  // --- psum: reduce over the 4 grp-lanes sharing lan (q = qt*16+lan) ---
#pragma unroll
  for (int qt = 0; qt < 2; ++qt) {
    psum[qt] += __shfl_xor(psum[qt], 16);
    psum[qt] += __shfl_xor(psum[qt], 32);
  }

  // --- epilogue: o = (o_causal + SufV) / (psum + (2047-q)) ---
  const size_t outbase = (size_t)(hd >> 4) * S_ * (N_ * H_) + (size_t)(hd & 15) * H_;
#pragma unroll
  for (int qt = 0; qt < 2; ++qt) {
#pragma unroll
    for (int r = 0; r < 4; ++r) {
      const int q_g = qw + qt * 16 + grp * 4 + r;
      const float ps = __shfl(psum[qt], grp * 4 + r);
      const float inv = 1.0f / (ps + (float)(2047 - q_g));
#pragma unroll
      for (int hf = 0; hf < 4; ++hf) {
        const int h = hf * 16 + lan;
        const float suf = Sufh[(size_t)q_g * H_ + h];
        Wtd[outbase + (size_t)q_g * (N_ * H_) + h] = (bf16)((o[qt][hf][r] + suf) * inv);
      }
    }
  }
}

// ---------------------------------------------------------------------------
extern "C" void kernel_launch(void* const* d_in, const int* in_sizes, int n_in,
                              void* d_out, int out_size, void* d_ws, size_t ws_size,
                              hipStream_t stream) {
  const float* residual = (const float*)d_in[0];
  const float* Wk = (const float*)d_in[1];
  const float* Wq = (const float*)d_in[2];
  const float* Wv = (const float*)d_in[3];
  const float* Wo = (const float*)d_in[4];
  const float* Bk = (const float*)d_in[5];
  const float* Bq = (const float*)d_in[6];
  const float* Bv = (const float*)d_in[7];
  const float* Bo = (const float*)d_in[8];
  float* outp = (float*)d_out;

  char* ws = (char*)d_ws;
  const size_t MB = 1024 * 1024;
  bf16* Abf = (bf16*)(ws + 0 * MB);    // [4096][1024] bf16 (8MB); later Wtd
  bf16* Wot = (bf16*)(ws + 8 * MB);    // [1024(e)][1024(nh)] (2MB, live to end)
  bf16* Wkt = (bf16*)(ws + 10 * MB);   // 3 x [1024][1024] (6MB)
  bf16* Kp  = (bf16*)(ws + 16 * MB);   // [hd][S][H] (8MB)
  bf16* Qp  = (bf16*)(ws + 24 * MB);   // (8MB)
  bf16* Vp  = (bf16*)(ws + 32 * MB);   // (8MB)
  bf16* Vtp = (bf16*)(ws + 40 * MB);   // [hd][H][S] (8MB)
  float* tot = (float*)(ws + 48 * MB); // [32][16][64] fp32 (128KB)
  bf16* Wtd = Abf;                     // aliases Abf (dead after gemm_proj)
  float* Suf = (float*)d_out;          // d_out as fp32 scratch until gemm_out
  (void)in_sizes; (void)n_in; (void)out_size; (void)ws_size;

  // residual fp32 -> bf16
  cvt_kernel<<<2048, 256, 0, stream>>>(residual, Abf, (B_ * S_ * D_) / 8);

  // weight transposes (QKV merged into one dispatch)
  qkvw_transpose_kernel<<<dim3(16, 1, 48), 256, 0, stream>>>(Wk, Wq, Wv, Wkt);
  transpose_f32bf16_kernel<<<dim3(16, 16, 1), 256, 0, stream>>>(Wo, Wot, 1024, 1024);

  // QKV projections (K->Kp, Q->Qp, V->Vp)
  gemm_proj_kernel<<<dim3(8, 32, 3), 256, 0, stream>>>(Abf, Wkt, Bk, Bq, Bv, Kp);

  // suffix-V (masked-mass numerator), fp32 into d_out scratch
  sufv_tot_kernel<<<dim3(32, 16), 64, 0, stream>>>(Vp, tot);
  sufv_scan_kernel<<<dim3(32, 16), 64, 0, stream>>>(Vp, tot, Suf);

  // V per-head transpose [S][H] -> [H][S]
  transpose_bf16_kernel<<<dim3(32, 1, 32), 256, 0, stream>>>(Vp, Vtp, 2048, 64);

  // attention (causal tiles only; writes Wtd over dead Abf)
  attn_kernel<<<512, 256, 0, stream>>>(Qp, Kp, Vtp, Suf, Wtd);

  // output projection -> fp32 d_out (overwrites Suf scratch)
  gemm_out_kernel<<<dim3(8, 32, 1), 256, 0, stream>>>(Wtd, Wot, Bo, outp);

  (void)Qp;
}